// Round 6
// baseline (3026.437 us; speedup 1.0000x reference)
//
#include <hip/hip_runtime.h>
#include <hip/hip_fp16.h>

__device__ __forceinline__ float h2f(__half v) { return __half2float(v); }
__device__ __forceinline__ __half f2h(float v) { return __float2half(v); }

#define SCAN_CHUNK 2048

// ---------------------------------------------------------------- sentinel: zero output (ws too small)
__global__ void zero_out_kernel(float* __restrict__ out, int total) {
    int i = blockIdx.x * blockDim.x + threadIdx.x;
    if (i < total) out[i] = 0.0f;
}

// ---------------------------------------------------------------- init: ego(fp16) = concat(user,item), macc(fp32) = ego
__global__ void init_kernel(const float* __restrict__ user, const float* __restrict__ item,
                            __half* __restrict__ ego, float* __restrict__ macc,
                            int usz, int total) {
    int i = blockIdx.x * blockDim.x + threadIdx.x;
    if (i >= total) return;
    float f = (i < usz) ? user[i] : item[i - usz];
    ego[i]  = f2h(f);
    macc[i] = f;
}

// ---------------------------------------------------------------- CSR build
__global__ void hist_kernel(const int* __restrict__ rows, int* __restrict__ cnt, int nnz) {
    int i = blockIdx.x * blockDim.x + threadIdx.x;
    if (i < nnz) atomicAdd(&cnt[rows[i]], 1);
}

// hierarchical exclusive scan over cnt[n]: pass1 block sums, pass2 scan sums, pass3 apply
__global__ void scan_pass1(const int* __restrict__ cnt, int* __restrict__ bsum, int n) {
    __shared__ int wt[4];
    int tid = threadIdx.x;
    int base = blockIdx.x * SCAN_CHUNK + tid * 8;
    int s = 0;
    #pragma unroll
    for (int k = 0; k < 8; ++k) { int i = base + k; if (i < n) s += cnt[i]; }
    #pragma unroll
    for (int o = 32; o > 0; o >>= 1) s += __shfl_down(s, o, 64);
    int lane = tid & 63, wid = tid >> 6;
    if (lane == 0) wt[wid] = s;
    __syncthreads();
    if (tid == 0) bsum[blockIdx.x] = wt[0] + wt[1] + wt[2] + wt[3];
}

__global__ void scan_pass2(int* __restrict__ bsum, int nb, int* __restrict__ total) {
    if (threadIdx.x == 0) {
        int run = 0;
        for (int b = 0; b < nb; ++b) { int v = bsum[b]; bsum[b] = run; run += v; }
        *total = run;
    }
}

__global__ void scan_pass3(int* __restrict__ cnt, const int* __restrict__ bsum,
                           int* __restrict__ rptr, int n, const int* __restrict__ total) {
    __shared__ int wt[4];
    int tid = threadIdx.x;
    int base = blockIdx.x * SCAN_CHUNK + tid * 8;
    int v[8];
    int s = 0;
    #pragma unroll
    for (int k = 0; k < 8; ++k) { int i = base + k; v[k] = (i < n) ? cnt[i] : 0; s += v[k]; }
    int lane = tid & 63, wid = tid >> 6;
    int xs = s;
    #pragma unroll
    for (int o = 1; o < 64; o <<= 1) { int t = __shfl_up(xs, o, 64); if (lane >= o) xs += t; }
    if (lane == 63) wt[wid] = xs;
    __syncthreads();
    int wexcl = 0;
    for (int w = 0; w < wid; ++w) wexcl += wt[w];
    int run = bsum[blockIdx.x] + wexcl + (xs - s);
    #pragma unroll
    for (int k = 0; k < 8; ++k) {
        int i = base + k;
        if (i < n) { rptr[i] = run; cnt[i] = run; }  // cnt becomes scatter cursor
        run += v[k];
    }
    if (blockIdx.x == 0 && tid == 0) rptr[n] = *total;
}

// paired edge record: {col, val_bits} -> one 8B store per edge
__global__ void scatter_kernel(const int* __restrict__ rows, const int* __restrict__ cols,
                               const float* __restrict__ vals, int* __restrict__ cursor,
                               int2* __restrict__ edges, int nnz) {
    int i = blockIdx.x * blockDim.x + threadIdx.x;
    if (i >= nnz) return;
    int r = rows[i];
    int pos = atomicAdd(&cursor[r], 1);
    edges[pos] = make_int2(cols[i], __float_as_int(vals[i]));
}

// ---------------------------------------------------------------- SpMM: aggE = A * ego  (single gather array)
// wave handles 2 rows, one per half-wave; each lane holds features 2f,2f+1 (half2); unroll x4.
__global__ void spmm_kernel(const int* __restrict__ rptr, const int2* __restrict__ edges,
                            const __half* __restrict__ ego, __half* __restrict__ aggE, int n) {
    int tid = threadIdx.x;
    int lane = tid & 63, wid = tid >> 6;
    int half_ = lane >> 5, f = lane & 31;
    int row = blockIdx.x * 8 + wid * 2 + half_;
    bool active = row < n;
    int beg = active ? rptr[row] : 0;
    int end = active ? rptr[row + 1] : 0;
    float2 acc = {0.f, 0.f};
    int j = beg;
    for (; j + 4 <= end; j += 4) {
        int2 e0 = edges[j], e1 = edges[j + 1], e2 = edges[j + 2], e3 = edges[j + 3];
        float2 g0 = __half22float2(*(const __half2*)(ego + ((size_t)e0.x << 6) + 2 * f));
        float2 g1 = __half22float2(*(const __half2*)(ego + ((size_t)e1.x << 6) + 2 * f));
        float2 g2 = __half22float2(*(const __half2*)(ego + ((size_t)e2.x << 6) + 2 * f));
        float2 g3 = __half22float2(*(const __half2*)(ego + ((size_t)e3.x << 6) + 2 * f));
        float v0 = __int_as_float(e0.y), v1 = __int_as_float(e1.y);
        float v2 = __int_as_float(e2.y), v3 = __int_as_float(e3.y);
        acc.x += v0 * g0.x + v1 * g1.x + v2 * g2.x + v3 * g3.x;
        acc.y += v0 * g0.y + v1 * g1.y + v2 * g2.y + v3 * g3.y;
    }
    for (; j < end; ++j) {
        int2 e = edges[j];
        float v = __int_as_float(e.y);
        float2 g = __half22float2(*(const __half2*)(ego + ((size_t)e.x << 6) + 2 * f));
        acc.x += v * g.x;
        acc.y += v * g.y;
    }
    if (active) ((__half2*)aggE)[(size_t)row * 32 + f] = __float22half2_rn(acc);
}

// ---------------------------------------------------------------- fused layer epilogue:
// s = aggE + ego; p = aggE * ego; e = leaky([s p] @ [w1;w2]); ego_out = e; macc += e
// 2 rows per wave (half2), K=128 shfl-broadcast; wcat staged fp32 in LDS (32KB).
__global__ void gemm_fused_kernel(const __half* __restrict__ aggE, const __half* __restrict__ ego,
                                  const float* __restrict__ w1k, const float* __restrict__ w2k,
                                  __half* __restrict__ ego_out, float* __restrict__ macc, int n) {
    __shared__ float wl[128 * 64];
    int tid = threadIdx.x;
    for (int i = tid; i < 4096; i += 256) {
        wl[i]        = w1k[i];
        wl[4096 + i] = w2k[i];
    }
    __syncthreads();
    int lane = tid & 63, wid = tid >> 6;
    int half_ = lane >> 5, f = lane & 31;
    int row = blockIdx.x * 8 + wid * 2 + half_;
    bool active = row < n;
    size_t off2 = (size_t)(active ? row : 0) * 32 + f;
    float2 x = __half22float2(((const __half2*)ego)[off2]);
    float2 a = __half22float2(((const __half2*)aggE)[off2]);
    float2 s2 = {a.x + x.x, a.y + x.y};
    float2 p2 = {a.x * x.x, a.y * x.y};
    float2 acc = {0.f, 0.f};
    #pragma unroll
    for (int j = 0; j < 64; ++j) {
        int srcl = (lane & 32) + (j >> 1);
        float av = __shfl((j & 1) ? s2.y : s2.x, srcl, 64);
        float2 wv = *(const float2*)&wl[j * 64 + 2 * f];
        acc.x += av * wv.x;
        acc.y += av * wv.y;
    }
    #pragma unroll
    for (int j = 0; j < 64; ++j) {
        int srcl = (lane & 32) + (j >> 1);
        float av = __shfl((j & 1) ? p2.y : p2.x, srcl, 64);
        float2 wv = *(const float2*)&wl[(64 + j) * 64 + 2 * f];
        acc.x += av * wv.x;
        acc.y += av * wv.y;
    }
    if (active) {
        float ex = (acc.x > 0.f) ? acc.x : 0.01f * acc.x;
        float ey = (acc.y > 0.f) ? acc.y : 0.01f * acc.y;
        ((__half2*)ego_out)[off2] = __float22half2_rn(make_float2(ex, ey));
        float2 m = ((float2*)macc)[off2];
        m.x += ex; m.y += ey;
        ((float2*)macc)[off2] = m;
    }
}

// ---------------------------------------------------------------- mean -> fp32 out (with CSR-sanity sentinel)
__global__ void finalize_kernel(const float* __restrict__ macc, float* __restrict__ out,
                                const int* __restrict__ rptr, int N, int nnz,
                                float scale, int total) {
    int i = blockIdx.x * blockDim.x + threadIdx.x;
    if (i >= total) return;
    bool ok = (rptr[N] == nnz);
    out[i] = ok ? macc[i] * scale : 0.75f;  // 0.75 sentinel => scan/CSR bug
}

extern "C" void kernel_launch(void* const* d_in, const int* in_sizes, int n_in,
                              void* d_out, int out_size, void* d_ws, size_t ws_size,
                              hipStream_t stream) {
    const float* user = (const float*)d_in[0];
    const float* item = (const float*)d_in[1];
    const float* w1   = (const float*)d_in[2];
    const float* w2   = (const float*)d_in[3];
    const float* vals = (const float*)d_in[4];
    const int*   rows = (const int*)d_in[5];
    const int*   cols = (const int*)d_in[6];

    const int usz = in_sizes[0];
    const int isz = in_sizes[1];
    const int L   = in_sizes[2] / 4096;
    const int nnz = in_sizes[4];
    const int N   = (usz + isz) / 64;
    const int ND  = N * 64;
    const int nb  = (N + SCAN_CHUNK - 1) / SCAN_CHUNK;

    char* p = (char*)d_ws;
    auto alloc = [&](size_t bytes) -> void* {
        void* r = (void*)p;
        p += (bytes + 255) & ~(size_t)255;
        return r;
    };
    __half* egoA  = (__half*)alloc((size_t)ND * 2);
    __half* egoB  = (__half*)alloc((size_t)ND * 2);
    __half* aggE  = (__half*)alloc((size_t)ND * 2);
    float*  macc  = (float*)alloc((size_t)ND * 4);
    int2*   edges = (int2*)alloc((size_t)nnz * 8);
    int*    rptr  = (int*)alloc((size_t)(N + 1) * 4);
    int*    cnt   = (int*)alloc((size_t)N * 4);
    int*    bsum  = (int*)alloc((size_t)nb * 4);
    int*    total = (int*)alloc(4);
    size_t need = (size_t)(p - (char*)d_ws);
    (void)n_in; (void)out_size;

    if (need > ws_size) {
        zero_out_kernel<<<(ND + 255) / 256, 256, 0, stream>>>((float*)d_out, ND);
        return;
    }

    hipMemsetAsync(cnt, 0, (size_t)N * 4, stream);

    init_kernel<<<(ND + 255) / 256, 256, 0, stream>>>(user, item, egoA, macc, usz, ND);
    hist_kernel<<<(nnz + 255) / 256, 256, 0, stream>>>(rows, cnt, nnz);
    scan_pass1<<<nb, 256, 0, stream>>>(cnt, bsum, N);
    scan_pass2<<<1, 64, 0, stream>>>(bsum, nb, total);
    scan_pass3<<<nb, 256, 0, stream>>>(cnt, bsum, rptr, N, total);
    scatter_kernel<<<(nnz + 255) / 256, 256, 0, stream>>>(rows, cols, vals, cnt, edges, nnz);

    const int rb8 = (N + 7) / 8;
    __half* ego_in  = egoA;
    __half* ego_out = egoB;
    for (int k = 0; k < L; ++k) {
        spmm_kernel<<<rb8, 256, 0, stream>>>(rptr, edges, ego_in, aggE, N);
        gemm_fused_kernel<<<rb8, 256, 0, stream>>>(aggE, ego_in, w1 + (size_t)k * 4096,
                                                   w2 + (size_t)k * 4096, ego_out, macc, N);
        __half* t = ego_in; ego_in = ego_out; ego_out = t;
    }
    finalize_kernel<<<(ND + 255) / 256, 256, 0, stream>>>(macc, (float*)d_out, rptr, N, nnz,
                                                          1.0f / (float)(L + 1), ND);
}

// Round 7
// 1532.812 us; speedup vs baseline: 1.9744x; 1.9744x over previous
//
#include <hip/hip_runtime.h>
#include <hip/hip_fp16.h>

__device__ __forceinline__ float h2f(__half v) { return __half2float(v); }
__device__ __forceinline__ __half f2h(float v) { return __float2half(v); }

#define SCAN_CHUNK 2048

// ---------------------------------------------------------------- sentinel: zero output (ws too small)
__global__ void zero_out_kernel(float* __restrict__ out, int total) {
    int i = blockIdx.x * blockDim.x + threadIdx.x;
    if (i < total) out[i] = 0.0f;
}

// ---------------------------------------------------------------- init: ego(fp16) = concat(user,item), macc(fp32) = ego
__global__ void init_kernel(const float* __restrict__ user, const float* __restrict__ item,
                            __half* __restrict__ ego, float* __restrict__ macc,
                            int usz, int total) {
    int i = blockIdx.x * blockDim.x + threadIdx.x;
    if (i >= total) return;
    float f = (i < usz) ? user[i] : item[i - usz];
    ego[i]  = f2h(f);
    macc[i] = f;
}

// ---------------------------------------------------------------- CSR build
__global__ void hist_kernel(const int* __restrict__ rows, int* __restrict__ cnt, int nnz) {
    int i = blockIdx.x * blockDim.x + threadIdx.x;
    if (i < nnz) atomicAdd(&cnt[rows[i]], 1);
}

// hierarchical exclusive scan over cnt[n]: pass1 block sums, pass2 scan sums, pass3 apply
__global__ void scan_pass1(const int* __restrict__ cnt, int* __restrict__ bsum, int n) {
    __shared__ int wt[4];
    int tid = threadIdx.x;
    int base = blockIdx.x * SCAN_CHUNK + tid * 8;
    int s = 0;
    #pragma unroll
    for (int k = 0; k < 8; ++k) { int i = base + k; if (i < n) s += cnt[i]; }
    #pragma unroll
    for (int o = 32; o > 0; o >>= 1) s += __shfl_down(s, o, 64);
    int lane = tid & 63, wid = tid >> 6;
    if (lane == 0) wt[wid] = s;
    __syncthreads();
    if (tid == 0) bsum[blockIdx.x] = wt[0] + wt[1] + wt[2] + wt[3];
}

__global__ void scan_pass2(int* __restrict__ bsum, int nb, int* __restrict__ total) {
    if (threadIdx.x == 0) {
        int run = 0;
        for (int b = 0; b < nb; ++b) { int v = bsum[b]; bsum[b] = run; run += v; }
        *total = run;
    }
}

__global__ void scan_pass3(int* __restrict__ cnt, const int* __restrict__ bsum,
                           int* __restrict__ rptr, int n, const int* __restrict__ total) {
    __shared__ int wt[4];
    int tid = threadIdx.x;
    int base = blockIdx.x * SCAN_CHUNK + tid * 8;
    int v[8];
    int s = 0;
    #pragma unroll
    for (int k = 0; k < 8; ++k) { int i = base + k; v[k] = (i < n) ? cnt[i] : 0; s += v[k]; }
    int lane = tid & 63, wid = tid >> 6;
    int xs = s;
    #pragma unroll
    for (int o = 1; o < 64; o <<= 1) { int t = __shfl_up(xs, o, 64); if (lane >= o) xs += t; }
    if (lane == 63) wt[wid] = xs;
    __syncthreads();
    int wexcl = 0;
    for (int w = 0; w < wid; ++w) wexcl += wt[w];
    int run = bsum[blockIdx.x] + wexcl + (xs - s);
    #pragma unroll
    for (int k = 0; k < 8; ++k) {
        int i = base + k;
        if (i < n) { rptr[i] = run; cnt[i] = run; }  // cnt becomes scatter cursor
        run += v[k];
    }
    if (blockIdx.x == 0 && tid == 0) rptr[n] = *total;
}

// paired edge record: {col, val_bits} -> one 8B store per edge
__global__ void scatter_kernel(const int* __restrict__ rows, const int* __restrict__ cols,
                               const float* __restrict__ vals, int* __restrict__ cursor,
                               int2* __restrict__ edges, int nnz) {
    int i = blockIdx.x * blockDim.x + threadIdx.x;
    if (i >= nnz) return;
    int r = rows[i];
    int pos = atomicAdd(&cursor[r], 1);
    edges[pos] = make_int2(cols[i], __float_as_int(vals[i]));
}

// ---------------------------------------------------------------- SpMM: aggE = A * ego  (single gather array)
// wave handles 2 rows, one per half-wave; each lane holds features 2f,2f+1 (half2); unroll x4.
__global__ void spmm_kernel(const int* __restrict__ rptr, const int2* __restrict__ edges,
                            const __half* __restrict__ ego, __half* __restrict__ aggE, int n) {
    int tid = threadIdx.x;
    int lane = tid & 63, wid = tid >> 6;
    int half_ = lane >> 5, f = lane & 31;
    int row = blockIdx.x * 8 + wid * 2 + half_;
    bool active = row < n;
    int beg = active ? rptr[row] : 0;
    int end = active ? rptr[row + 1] : 0;
    float2 acc = {0.f, 0.f};
    int j = beg;
    for (; j + 4 <= end; j += 4) {
        int2 e0 = edges[j], e1 = edges[j + 1], e2 = edges[j + 2], e3 = edges[j + 3];
        float2 g0 = __half22float2(*(const __half2*)(ego + ((size_t)e0.x << 6) + 2 * f));
        float2 g1 = __half22float2(*(const __half2*)(ego + ((size_t)e1.x << 6) + 2 * f));
        float2 g2 = __half22float2(*(const __half2*)(ego + ((size_t)e2.x << 6) + 2 * f));
        float2 g3 = __half22float2(*(const __half2*)(ego + ((size_t)e3.x << 6) + 2 * f));
        float v0 = __int_as_float(e0.y), v1 = __int_as_float(e1.y);
        float v2 = __int_as_float(e2.y), v3 = __int_as_float(e3.y);
        acc.x += v0 * g0.x + v1 * g1.x + v2 * g2.x + v3 * g3.x;
        acc.y += v0 * g0.y + v1 * g1.y + v2 * g2.y + v3 * g3.y;
    }
    for (; j < end; ++j) {
        int2 e = edges[j];
        float v = __int_as_float(e.y);
        float2 g = __half22float2(*(const __half2*)(ego + ((size_t)e.x << 6) + 2 * f));
        acc.x += v * g.x;
        acc.y += v * g.y;
    }
    if (active) ((__half2*)aggE)[(size_t)row * 32 + f] = __float22half2_rn(acc);
}

// ---------------------------------------------------------------- fused layer epilogue (proven scalar shape):
// s = aggE + ego; p = aggE * ego; e = leaky([s p] @ [w1;w2]); ego_out = e; macc += e
// one row per wave, scalar shfl-broadcast K=128; weights staged fp32 in LDS (32KB).
__global__ __launch_bounds__(256, 4)
void layer_epi_kernel(const __half* __restrict__ aggE, const __half* __restrict__ ego,
                      const float* __restrict__ w1k, const float* __restrict__ w2k,
                      __half* __restrict__ ego_out, float* __restrict__ macc, int n) {
    __shared__ float wl[128 * 64];
    int tid = threadIdx.x;
    for (int i = tid; i < 4096; i += 256) {
        wl[i]        = w1k[i];
        wl[4096 + i] = w2k[i];
    }
    __syncthreads();
    int lane = tid & 63, wid = tid >> 6;
    int row = blockIdx.x * 4 + wid;
    bool active = row < n;
    size_t off = (size_t)(active ? row : 0) * 64 + lane;
    float x = h2f(ego[off]);
    float a = h2f(aggE[off]);
    float s = a + x;
    float pp = a * x;
    float acc = 0.f;
    #pragma unroll
    for (int j = 0; j < 64; ++j) acc += __shfl(s, j, 64) * wl[j * 64 + lane];
    #pragma unroll
    for (int j = 0; j < 64; ++j) acc += __shfl(pp, j, 64) * wl[(64 + j) * 64 + lane];
    if (active) {
        float e = (acc > 0.f) ? acc : 0.01f * acc;
        ego_out[off] = f2h(e);
        macc[off] += e;
    }
}

// ---------------------------------------------------------------- mean -> fp32 out (with CSR-sanity sentinel)
__global__ void finalize_kernel(const float* __restrict__ macc, float* __restrict__ out,
                                const int* __restrict__ rptr, int N, int nnz,
                                float scale, int total) {
    int i = blockIdx.x * blockDim.x + threadIdx.x;
    if (i >= total) return;
    bool ok = (rptr[N] == nnz);
    out[i] = ok ? macc[i] * scale : 0.75f;  // 0.75 sentinel => scan/CSR bug
}

extern "C" void kernel_launch(void* const* d_in, const int* in_sizes, int n_in,
                              void* d_out, int out_size, void* d_ws, size_t ws_size,
                              hipStream_t stream) {
    const float* user = (const float*)d_in[0];
    const float* item = (const float*)d_in[1];
    const float* w1   = (const float*)d_in[2];
    const float* w2   = (const float*)d_in[3];
    const float* vals = (const float*)d_in[4];
    const int*   rows = (const int*)d_in[5];
    const int*   cols = (const int*)d_in[6];

    const int usz = in_sizes[0];
    const int isz = in_sizes[1];
    const int L   = in_sizes[2] / 4096;
    const int nnz = in_sizes[4];
    const int N   = (usz + isz) / 64;
    const int ND  = N * 64;
    const int nb  = (N + SCAN_CHUNK - 1) / SCAN_CHUNK;

    char* p = (char*)d_ws;
    auto alloc = [&](size_t bytes) -> void* {
        void* r = (void*)p;
        p += (bytes + 255) & ~(size_t)255;
        return r;
    };
    __half* egoA  = (__half*)alloc((size_t)ND * 2);
    __half* egoB  = (__half*)alloc((size_t)ND * 2);
    __half* aggE  = (__half*)alloc((size_t)ND * 2);
    float*  macc  = (float*)alloc((size_t)ND * 4);
    int2*   edges = (int2*)alloc((size_t)nnz * 8);
    int*    rptr  = (int*)alloc((size_t)(N + 1) * 4);
    int*    cnt   = (int*)alloc((size_t)N * 4);
    int*    bsum  = (int*)alloc((size_t)nb * 4);
    int*    total = (int*)alloc(4);
    size_t need = (size_t)(p - (char*)d_ws);
    (void)n_in; (void)out_size;

    if (need > ws_size) {
        zero_out_kernel<<<(ND + 255) / 256, 256, 0, stream>>>((float*)d_out, ND);
        return;
    }

    hipMemsetAsync(cnt, 0, (size_t)N * 4, stream);

    init_kernel<<<(ND + 255) / 256, 256, 0, stream>>>(user, item, egoA, macc, usz, ND);
    hist_kernel<<<(nnz + 255) / 256, 256, 0, stream>>>(rows, cnt, nnz);
    scan_pass1<<<nb, 256, 0, stream>>>(cnt, bsum, N);
    scan_pass2<<<1, 64, 0, stream>>>(bsum, nb, total);
    scan_pass3<<<nb, 256, 0, stream>>>(cnt, bsum, rptr, N, total);
    scatter_kernel<<<(nnz + 255) / 256, 256, 0, stream>>>(rows, cols, vals, cnt, edges, nnz);

    const int rb8 = (N + 7) / 8;
    const int rb4 = (N + 3) / 4;
    __half* ego_in  = egoA;
    __half* ego_out = egoB;
    for (int k = 0; k < L; ++k) {
        spmm_kernel<<<rb8, 256, 0, stream>>>(rptr, edges, ego_in, aggE, N);
        layer_epi_kernel<<<rb4, 256, 0, stream>>>(aggE, ego_in, w1 + (size_t)k * 4096,
                                                  w2 + (size_t)k * 4096, ego_out, macc, N);
        __half* t = ego_in; ego_in = ego_out; ego_out = t;
    }
    finalize_kernel<<<(ND + 255) / 256, 256, 0, stream>>>(macc, (float*)d_out, rptr, N, nnz,
                                                          1.0f / (float)(L + 1), ND);
}

// Round 8
// 633.918 us; speedup vs baseline: 4.7742x; 2.4180x over previous
//
#include <hip/hip_runtime.h>
#include <hip/hip_fp16.h>

typedef _Float16 f16;
typedef _Float16 f16x8 __attribute__((ext_vector_type(8)));
typedef float f32x4 __attribute__((ext_vector_type(4)));

__device__ __forceinline__ float h2f(__half v) { return __half2float(v); }
__device__ __forceinline__ __half f2h(float v) { return __float2half(v); }

#define SCAN_CHUNK 2048
#define ASTRIDE 136  // 128 + 8 pad; 272B row stride, 16B-aligned

// ---------------------------------------------------------------- sentinel: zero output (ws too small)
__global__ void zero_out_kernel(float* __restrict__ out, int total) {
    int i = blockIdx.x * blockDim.x + threadIdx.x;
    if (i < total) out[i] = 0.0f;
}

// ---------------------------------------------------------------- init: ego0(fp16) = concat(user,item)
__global__ void init_kernel(const float* __restrict__ user, const float* __restrict__ item,
                            __half* __restrict__ ego0, int usz, int total) {
    int i = blockIdx.x * blockDim.x + threadIdx.x;
    if (i >= total) return;
    float f = (i < usz) ? user[i] : item[i - usz];
    ego0[i] = f2h(f);
}

// ---------------------------------------------------------------- CSR build
__global__ void hist_kernel(const int* __restrict__ rows, int* __restrict__ cnt, int nnz) {
    int i = blockIdx.x * blockDim.x + threadIdx.x;
    if (i < nnz) atomicAdd(&cnt[rows[i]], 1);
}

__global__ void scan_pass1(const int* __restrict__ cnt, int* __restrict__ bsum, int n) {
    __shared__ int wt[4];
    int tid = threadIdx.x;
    int base = blockIdx.x * SCAN_CHUNK + tid * 8;
    int s = 0;
    #pragma unroll
    for (int k = 0; k < 8; ++k) { int i = base + k; if (i < n) s += cnt[i]; }
    #pragma unroll
    for (int o = 32; o > 0; o >>= 1) s += __shfl_down(s, o, 64);
    int lane = tid & 63, wid = tid >> 6;
    if (lane == 0) wt[wid] = s;
    __syncthreads();
    if (tid == 0) bsum[blockIdx.x] = wt[0] + wt[1] + wt[2] + wt[3];
}

__global__ void scan_pass2(int* __restrict__ bsum, int nb, int* __restrict__ total) {
    if (threadIdx.x == 0) {
        int run = 0;
        for (int b = 0; b < nb; ++b) { int v = bsum[b]; bsum[b] = run; run += v; }
        *total = run;
    }
}

__global__ void scan_pass3(int* __restrict__ cnt, const int* __restrict__ bsum,
                           int* __restrict__ rptr, int n, const int* __restrict__ total) {
    __shared__ int wt[4];
    int tid = threadIdx.x;
    int base = blockIdx.x * SCAN_CHUNK + tid * 8;
    int v[8];
    int s = 0;
    #pragma unroll
    for (int k = 0; k < 8; ++k) { int i = base + k; v[k] = (i < n) ? cnt[i] : 0; s += v[k]; }
    int lane = tid & 63, wid = tid >> 6;
    int xs = s;
    #pragma unroll
    for (int o = 1; o < 64; o <<= 1) { int t = __shfl_up(xs, o, 64); if (lane >= o) xs += t; }
    if (lane == 63) wt[wid] = xs;
    __syncthreads();
    int wexcl = 0;
    for (int w = 0; w < wid; ++w) wexcl += wt[w];
    int run = bsum[blockIdx.x] + wexcl + (xs - s);
    #pragma unroll
    for (int k = 0; k < 8; ++k) {
        int i = base + k;
        if (i < n) { rptr[i] = run; cnt[i] = run; }  // cnt becomes scatter cursor
        run += v[k];
    }
    if (blockIdx.x == 0 && tid == 0) rptr[n] = *total;
}

// paired edge record: {col, val_bits}
__global__ void scatter_kernel(const int* __restrict__ rows, const int* __restrict__ cols,
                               const float* __restrict__ vals, int* __restrict__ cursor,
                               int2* __restrict__ edges, int nnz) {
    int i = blockIdx.x * blockDim.x + threadIdx.x;
    if (i >= nnz) return;
    int r = rows[i];
    int pos = atomicAdd(&cursor[r], 1);
    edges[pos] = make_int2(cols[i], __float_as_int(vals[i]));
}

// ---------------------------------------------------------------- SpMM: aggE = A * ego (2 rows/wave, half2/lane, x4 unroll)
__global__ void spmm_kernel(const int* __restrict__ rptr, const int2* __restrict__ edges,
                            const __half* __restrict__ ego, __half* __restrict__ aggE, int n) {
    int tid = threadIdx.x;
    int lane = tid & 63, wid = tid >> 6;
    int half_ = lane >> 5, f = lane & 31;
    int row = blockIdx.x * 8 + wid * 2 + half_;
    bool active = row < n;
    int beg = active ? rptr[row] : 0;
    int end = active ? rptr[row + 1] : 0;
    float2 acc = {0.f, 0.f};
    int j = beg;
    for (; j + 4 <= end; j += 4) {
        int2 e0 = edges[j], e1 = edges[j + 1], e2 = edges[j + 2], e3 = edges[j + 3];
        float2 g0 = __half22float2(*(const __half2*)(ego + ((size_t)e0.x << 6) + 2 * f));
        float2 g1 = __half22float2(*(const __half2*)(ego + ((size_t)e1.x << 6) + 2 * f));
        float2 g2 = __half22float2(*(const __half2*)(ego + ((size_t)e2.x << 6) + 2 * f));
        float2 g3 = __half22float2(*(const __half2*)(ego + ((size_t)e3.x << 6) + 2 * f));
        float v0 = __int_as_float(e0.y), v1 = __int_as_float(e1.y);
        float v2 = __int_as_float(e2.y), v3 = __int_as_float(e3.y);
        acc.x += v0 * g0.x + v1 * g1.x + v2 * g2.x + v3 * g3.x;
        acc.y += v0 * g0.y + v1 * g1.y + v2 * g2.y + v3 * g3.y;
    }
    for (; j < end; ++j) {
        int2 e = edges[j];
        float v = __int_as_float(e.y);
        float2 g = __half22float2(*(const __half2*)(ego + ((size_t)e.x << 6) + 2 * f));
        acc.x += v * g.x;
        acc.y += v * g.y;
    }
    if (active) ((__half2*)aggE)[(size_t)row * 32 + f] = __float22half2_rn(acc);
}

// ---------------------------------------------------------------- MFMA layer: e = leaky([s p] @ [w1;w2])
// s = aggE+ego, p = aggE*ego. Block = 64 rows; A[64][128] f16 + Wt[64][128] f16 in LDS (stride 136).
// Wave w computes rows [w*16, w*16+16) x all 64 cols: 4 ks x 4 nt mfma_f32_16x16x32_f16.
__global__ __launch_bounds__(256, 4)
void layer_mfma_kernel(const __half* __restrict__ aggE, const __half* __restrict__ ego,
                       const float* __restrict__ w1k, const float* __restrict__ w2k,
                       __half* __restrict__ ego_out, int n) {
    __shared__ f16 A_lds[64 * ASTRIDE];
    __shared__ f16 Wt_lds[64 * ASTRIDE];
    int tid = threadIdx.x;
    // stage Wt[n][k]: k<64 -> w1[k][n], k>=64 -> w2[k-64][n]
    #pragma unroll
    for (int it = 0; it < 16; ++it) {
        int e = tid + it * 256;        // 4096 elements of each weight
        int k = e >> 6, c = e & 63;
        Wt_lds[c * ASTRIDE + k]      = (f16)w1k[e];
        Wt_lds[c * ASTRIDE + 64 + k] = (f16)w2k[e];
    }
    // stage A = [s | p] for 64 rows
    int base_row = blockIdx.x * 64;
    const __half2* a2p = (const __half2*)aggE;
    const __half2* x2p = (const __half2*)ego;
    #pragma unroll
    for (int it = 0; it < 8; ++it) {
        int idx = tid + it * 256;      // 2048 half2 slots
        int r = idx >> 5, c2 = idx & 31;
        int grow = base_row + r;
        size_t goff = (size_t)(grow < n ? grow : 0) * 32 + c2;
        float2 a = __half22float2(a2p[goff]);
        float2 x = __half22float2(x2p[goff]);
        f16* ar = &A_lds[r * ASTRIDE];
        ar[2 * c2]          = (f16)(a.x + x.x);
        ar[2 * c2 + 1]      = (f16)(a.y + x.y);
        ar[64 + 2 * c2]     = (f16)(a.x * x.x);
        ar[64 + 2 * c2 + 1] = (f16)(a.y * x.y);
    }
    __syncthreads();
    int lane = tid & 63, wid = tid >> 6;
    int m = lane & 15, q = lane >> 4;
    f32x4 acc0 = {0.f, 0.f, 0.f, 0.f}, acc1 = acc0, acc2 = acc0, acc3 = acc0;
    const f16* arow = &A_lds[(wid * 16 + m) * ASTRIDE + q * 8];
    const f16* brow = &Wt_lds[m * ASTRIDE + q * 8];
    #pragma unroll
    for (int ks = 0; ks < 4; ++ks) {
        f16x8 av = *(const f16x8*)(arow + ks * 32);
        f16x8 b0 = *(const f16x8*)(brow + ks * 32);
        f16x8 b1 = *(const f16x8*)(brow + 16 * ASTRIDE + ks * 32);
        f16x8 b2 = *(const f16x8*)(brow + 32 * ASTRIDE + ks * 32);
        f16x8 b3 = *(const f16x8*)(brow + 48 * ASTRIDE + ks * 32);
        acc0 = __builtin_amdgcn_mfma_f32_16x16x32_f16(av, b0, acc0, 0, 0, 0);
        acc1 = __builtin_amdgcn_mfma_f32_16x16x32_f16(av, b1, acc1, 0, 0, 0);
        acc2 = __builtin_amdgcn_mfma_f32_16x16x32_f16(av, b2, acc2, 0, 0, 0);
        acc3 = __builtin_amdgcn_mfma_f32_16x16x32_f16(av, b3, acc3, 0, 0, 0);
    }
    // C/D: row = q*4 + r (in 16-row tile), col = nt*16 + m
    int rbase = base_row + wid * 16 + q * 4;
    #pragma unroll
    for (int r = 0; r < 4; ++r) {
        int grow = rbase + r;
        if (grow < n) {
            size_t o = (size_t)grow * 64 + m;
            float e0 = acc0[r]; e0 = (e0 > 0.f) ? e0 : 0.01f * e0;
            float e1 = acc1[r]; e1 = (e1 > 0.f) ? e1 : 0.01f * e1;
            float e2 = acc2[r]; e2 = (e2 > 0.f) ? e2 : 0.01f * e2;
            float e3 = acc3[r]; e3 = (e3 > 0.f) ? e3 : 0.01f * e3;
            ego_out[o]      = f2h(e0);
            ego_out[o + 16] = f2h(e1);
            ego_out[o + 32] = f2h(e2);
            ego_out[o + 48] = f2h(e3);
        }
    }
}

// ---------------------------------------------------------------- finalize: out = mean(e0..e3) (with CSR sentinel)
__global__ void finalize4_kernel(const __half* __restrict__ e0, const __half* __restrict__ e1,
                                 const __half* __restrict__ e2, const __half* __restrict__ e3,
                                 float* __restrict__ out, const int* __restrict__ rptr,
                                 int N, int nnz, float scale, int total) {
    int i = blockIdx.x * blockDim.x + threadIdx.x;
    if (i >= total) return;
    bool ok = (rptr[N] == nnz);
    float s = h2f(e0[i]) + h2f(e1[i]) + h2f(e2[i]) + h2f(e3[i]);
    out[i] = ok ? s * scale : 0.75f;
}

// generic fallback accumulate (L != 3)
__global__ void acc_kernel(const __half* __restrict__ e, float* __restrict__ out,
                           float scale, int total, int first) {
    int i = blockIdx.x * blockDim.x + threadIdx.x;
    if (i >= total) return;
    float v = h2f(e[i]) * scale;
    out[i] = first ? v : out[i] + v;
}

extern "C" void kernel_launch(void* const* d_in, const int* in_sizes, int n_in,
                              void* d_out, int out_size, void* d_ws, size_t ws_size,
                              hipStream_t stream) {
    const float* user = (const float*)d_in[0];
    const float* item = (const float*)d_in[1];
    const float* w1   = (const float*)d_in[2];
    const float* w2   = (const float*)d_in[3];
    const float* vals = (const float*)d_in[4];
    const int*   rows = (const int*)d_in[5];
    const int*   cols = (const int*)d_in[6];

    const int usz = in_sizes[0];
    const int isz = in_sizes[1];
    const int L   = in_sizes[2] / 4096;
    const int nnz = in_sizes[4];
    const int N   = (usz + isz) / 64;
    const int ND  = N * 64;
    const int nb  = (N + SCAN_CHUNK - 1) / SCAN_CHUNK;

    char* p = (char*)d_ws;
    auto alloc = [&](size_t bytes) -> void* {
        void* r = (void*)p;
        p += (bytes + 255) & ~(size_t)255;
        return r;
    };
    __half* egos  = (__half*)alloc((size_t)(L + 1) * ND * 2);
    __half* aggE  = (__half*)alloc((size_t)ND * 2);
    int2*   edges = (int2*)alloc((size_t)nnz * 8);
    int*    rptr  = (int*)alloc((size_t)(N + 1) * 4);
    int*    cnt   = (int*)alloc((size_t)N * 4);
    int*    bsum  = (int*)alloc((size_t)nb * 4);
    int*    total = (int*)alloc(4);
    size_t need = (size_t)(p - (char*)d_ws);
    (void)n_in; (void)out_size;

    if (need > ws_size) {
        zero_out_kernel<<<(ND + 255) / 256, 256, 0, stream>>>((float*)d_out, ND);
        return;
    }

    hipMemsetAsync(cnt, 0, (size_t)N * 4, stream);

    init_kernel<<<(ND + 255) / 256, 256, 0, stream>>>(user, item, egos, usz, ND);
    hist_kernel<<<(nnz + 255) / 256, 256, 0, stream>>>(rows, cnt, nnz);
    scan_pass1<<<nb, 256, 0, stream>>>(cnt, bsum, N);
    scan_pass2<<<1, 64, 0, stream>>>(bsum, nb, total);
    scan_pass3<<<nb, 256, 0, stream>>>(cnt, bsum, rptr, N, total);
    scatter_kernel<<<(nnz + 255) / 256, 256, 0, stream>>>(rows, cols, vals, cnt, edges, nnz);

    const int rb8  = (N + 7) / 8;
    const int nb64 = (N + 63) / 64;
    for (int k = 0; k < L; ++k) {
        __half* ein  = egos + (size_t)k * ND;
        __half* eout = egos + (size_t)(k + 1) * ND;
        spmm_kernel<<<rb8, 256, 0, stream>>>(rptr, edges, ein, aggE, N);
        layer_mfma_kernel<<<nb64, 256, 0, stream>>>(aggE, ein, w1 + (size_t)k * 4096,
                                                    w2 + (size_t)k * 4096, eout, N);
    }
    float scale = 1.0f / (float)(L + 1);
    if (L == 3) {
        finalize4_kernel<<<(ND + 255) / 256, 256, 0, stream>>>(
            egos, egos + (size_t)ND, egos + (size_t)2 * ND, egos + (size_t)3 * ND,
            (float*)d_out, rptr, N, nnz, scale, ND);
    } else {
        for (int k = 0; k <= L; ++k)
            acc_kernel<<<(ND + 255) / 256, 256, 0, stream>>>(egos + (size_t)k * ND,
                                                             (float*)d_out, scale, ND, k == 0);
    }
}